// Round 3
// baseline (670.949 us; speedup 1.0000x reference)
//
#include <hip/hip_runtime.h>
#include <cstdint>
#include <cstddef>

typedef unsigned short ushort_t;
typedef __attribute__((ext_vector_type(8))) short short8;    // 8 bf16 (4 VGPRs)
typedef __attribute__((ext_vector_type(4))) float floatx4;

#define B_   32
#define T_   2048
#define H_   1024
#define U_   1024
#define KN_  32
#define KEXT 1056            // H + KN, = 33 * 32
#define BT_  (B_ * T_)       // 65536

// ---------- helpers ----------
__device__ __forceinline__ unsigned int f2bf_u(float f) {
    union { float f; unsigned int u; } v; v.f = f;
    unsigned int u = v.u;
    return (u + 0x7FFFu + ((u >> 16) & 1u)) >> 16;  // RNE
}
__device__ __forceinline__ float bflo(unsigned int u) {
    union { unsigned int u; float f; } v; v.u = u << 16; return v.f;
}
__device__ __forceinline__ float bfhi(unsigned int u) {
    union { unsigned int u; float f; } v; v.u = u & 0xffff0000u; return v.f;
}
__device__ __forceinline__ unsigned int pack2bf(float a, float b) {
    return f2bf_u(a) | (f2bf_u(b) << 16);
}
__device__ __forceinline__ void async_cp16(const void* g, void* l) {
    __builtin_amdgcn_global_load_lds(
        (const __attribute__((address_space(1))) unsigned int*)g,
        (__attribute__((address_space(3))) unsigned int*)l, 16, 0, 0);
}
__device__ __forceinline__ float fast_tanh(float x) {
    float e = __expf(2.0f * x);
    return 1.0f - 2.0f * __builtin_amdgcn_rcpf(e + 1.0f);
}

// ---------- fused pack: values->bf16 + conv(prev_att)->loc, full A rows ----------
// grid: 32 b * 32 t-chunks (64 rows each) = 1024 blocks, 256 threads
__global__ void pack_all(const float* __restrict__ values, const float* __restrict__ prev,
                         const float* __restrict__ convw, ushort_t* __restrict__ A) {
    __shared__ float sw[KN_ * 31];   // 3968 B
    __shared__ float satt[94];       // 64 + 2*15
    const int tid = threadIdx.x;
    const int b  = blockIdx.x >> 5;
    const int t0 = (blockIdx.x & 31) * 64;

    for (int i = tid; i < KN_ * 31; i += 256) sw[i] = convw[i];
    for (int i = tid; i < 94; i += 256) {
        int t = t0 - 15 + i;
        satt[i] = (t >= 0 && t < T_) ? prev[b * T_ + t] : 0.0f;
    }
    __syncthreads();

    // values: 64 rows x 1024 cols, 2 rows per pass, 16B stores
    const int colb = (tid & 127) * 8;
    const int rp   = tid >> 7;            // 0/1
#pragma unroll 4
    for (int pass = 0; pass < 32; ++pass) {
        const size_t g = (size_t)b * T_ + t0 + pass * 2 + rp;
        const float* vrow = values + g * H_ + colb;
        float4 v0 = *reinterpret_cast<const float4*>(vrow);
        float4 v1 = *reinterpret_cast<const float4*>(vrow + 4);
        uint4 o;
        o.x = pack2bf(v0.x, v0.y);
        o.y = pack2bf(v0.z, v0.w);
        o.z = pack2bf(v1.x, v1.y);
        o.w = pack2bf(v1.z, v1.w);
        *reinterpret_cast<uint4*>(A + g * KEXT + colb) = o;
    }

    // conv: thread -> row tl = tid>>2, k0 = (tid&3)*8 (8 consecutive k), 16B store
    const int tl = tid >> 2;
    const int k0 = (tid & 3) * 8;
    float acc[8] = {0, 0, 0, 0, 0, 0, 0, 0};
#pragma unroll
    for (int j = 0; j < 31; ++j) {
        const float p = satt[tl + j];
#pragma unroll
        for (int kk = 0; kk < 8; ++kk)
            acc[kk] += p * sw[(k0 + kk) * 31 + j];
    }
    uint4 o;
    o.x = pack2bf(acc[0], acc[1]);
    o.y = pack2bf(acc[2], acc[3]);
    o.z = pack2bf(acc[4], acc[5]);
    o.w = pack2bf(acc[6], acc[7]);
    *reinterpret_cast<uint4*>(A + ((size_t)b * T_ + t0 + tl) * KEXT + H_ + k0) = o;
}

// per u: pack [W1_w | loc_proj] row to Bm bf16 AND bias[b][u] for all 32 b
__global__ void pack_w_bias(const float* __restrict__ W1w, const float* __restrict__ locp,
                            const float* __restrict__ W2w, const float* __restrict__ q,
                            const float* __restrict__ W1b, const float* __restrict__ W2b,
                            ushort_t* __restrict__ Bm, float* __restrict__ bias) {
    const int u = blockIdx.x, tid = threadIdx.x;
    {
        const float* wrow = W1w + (size_t)u * H_ + tid * 4;
        float4 v = *reinterpret_cast<const float4*>(wrow);
        ushort4 o;
        o.x = (ushort_t)f2bf_u(v.x); o.y = (ushort_t)f2bf_u(v.y);
        o.z = (ushort_t)f2bf_u(v.z); o.w = (ushort_t)f2bf_u(v.w);
        *reinterpret_cast<ushort4*>(Bm + (size_t)u * KEXT + tid * 4) = o;
    }
    if (tid < 8) {
        float4 w = reinterpret_cast<const float4*>(locp + u * KN_)[tid];
        ushort4 o2;
        o2.x = (ushort_t)f2bf_u(w.x); o2.y = (ushort_t)f2bf_u(w.y);
        o2.z = (ushort_t)f2bf_u(w.z); o2.w = (ushort_t)f2bf_u(w.w);
        *reinterpret_cast<ushort4*>(Bm + (size_t)u * KEXT + H_ + tid * 4) = o2;
    }
    const int lane = tid & 63, wave = tid >> 6;
    const float* wr = W2w + (size_t)u * H_;
    float wv[16];
#pragma unroll
    for (int i = 0; i < 16; ++i) wv[i] = wr[lane + i * 64];
    const float bb = W1b[u] + W2b[u];
#pragma unroll
    for (int j = 0; j < 8; ++j) {
        const int b = wave * 8 + j;
        const float* qr = q + b * H_;
        float acc = 0.0f;
#pragma unroll
        for (int i = 0; i < 16; ++i) acc += wv[i] * qr[lane + i * 64];
#pragma unroll
        for (int off = 32; off >= 1; off >>= 1) acc += __shfl_xor(acc, off, 64);
        if (lane == 0) bias[b * U_ + u] = acc + bb;
    }
}

// ---------- fused score GEMM ----------
// XCD swizzle (xcd keyed to m, n fastest) + XOR-swizzled LDS chunks for
// conflict-free ds_read_b128 (each quad-phase hits all 8 bank-groups 2x).
__global__ __launch_bounds__(256, 2)
void score_gemm(const ushort_t* __restrict__ A, const ushort_t* __restrict__ Bm,
                const float* __restrict__ bias, const float* __restrict__ Vw,
                float* __restrict__ sacc) {
    __shared__ __align__(16) ushort_t lA[128 * 32];  // 8 KB
    __shared__ __align__(16) ushort_t lB[128 * 32];  // 8 KB
    const int tid  = threadIdx.x;
    const int wave = tid >> 6;
    const int lane = tid & 63;

    const int hid  = blockIdx.x;          // 0..4095
    const int xcd  = hid & 7;
    const int slot = hid >> 3;
    const int n_idx = slot & 7;
    const int m_idx = ((slot >> 3) << 3) | xcd;   // 0..511
    const int m0 = m_idx * 128;
    const int n0 = n_idx * 128;

    const int wm = (wave >> 1) * 64;
    const int wn = (wave & 1) * 64;
    const int lr   = lane & 15;
    const int quad = lane >> 4;

    floatx4 acc[4][4] = {};

    const ushort_t* Abase = A + (size_t)m0 * KEXT;
    const ushort_t* Bbase = Bm + (size_t)n0 * KEXT;

    // staging: slot s holds global chunk (row s>>2, col (s&3)^((s>>3)&3))
    const int s0 = wave * 64 + lane;
    const int s1 = (4 + wave) * 64 + lane;
    const int r0 = s0 >> 2, c0 = (s0 & 3) ^ ((s0 >> 3) & 3);
    const int r1 = s1 >> 2, c1 = (s1 & 3) ^ ((s1 >> 3) & 3);

    // fragment chunk xor (per-lane constant): quad ^ ((lr>>1)&3)
    const int cxor = (quad ^ ((lr >> 1) & 3)) * 8;

    for (int kk = 0; kk < 33; ++kk) {
        const int kb = kk * 32;
        async_cp16(Abase + (size_t)r0 * KEXT + kb + c0 * 8, lA + wave * 512);
        async_cp16(Abase + (size_t)r1 * KEXT + kb + c1 * 8, lA + (4 + wave) * 512);
        async_cp16(Bbase + (size_t)r0 * KEXT + kb + c0 * 8, lB + wave * 512);
        async_cp16(Bbase + (size_t)r1 * KEXT + kb + c1 * 8, lB + (4 + wave) * 512);
        __syncthreads();

        short8 af[4], bfr[4];
#pragma unroll
        for (int mi = 0; mi < 4; ++mi)
            af[mi] = *reinterpret_cast<const short8*>(lA + (wm + mi * 16 + lr) * 32 + cxor);
#pragma unroll
        for (int ni = 0; ni < 4; ++ni)
            bfr[ni] = *reinterpret_cast<const short8*>(lB + (wn + ni * 16 + lr) * 32 + cxor);
#pragma unroll
        for (int mi = 0; mi < 4; ++mi)
#pragma unroll
            for (int ni = 0; ni < 4; ++ni)
                acc[mi][ni] = __builtin_amdgcn_mfma_f32_16x16x32_bf16(af[mi], bfr[ni], acc[mi][ni], 0, 0, 0);
        __syncthreads();
    }

    // epilogue: sum_1 -> tanh -> *Vw -> reduce over u (cols) -> atomic partial score
    const int b = m0 >> 11;
    const float* brow = bias + b * U_;
    float vw[4], bv[4];
#pragma unroll
    for (int ni = 0; ni < 4; ++ni) {
        const int u = n0 + wn + ni * 16 + lr;
        vw[ni] = Vw[u];
        bv[ni] = brow[u];
    }
#pragma unroll
    for (int mi = 0; mi < 4; ++mi) {
#pragma unroll
        for (int r = 0; r < 4; ++r) {
            float s = 0.0f;
#pragma unroll
            for (int ni = 0; ni < 4; ++ni)
                s += vw[ni] * fast_tanh(acc[mi][ni][r] + bv[ni]);
            s += __shfl_xor(s, 1, 64);
            s += __shfl_xor(s, 2, 64);
            s += __shfl_xor(s, 4, 64);
            s += __shfl_xor(s, 8, 64);
            if (lr == 0)
                atomicAdd(&sacc[m0 + wm + mi * 16 + quad * 4 + r], s);
        }
    }
}

// ---------- softmax over T per b; writes score and attn outputs ----------
__global__ void softmax_k(const float* __restrict__ sacc, const float* __restrict__ Vb,
                          float* __restrict__ out) {
    const int b = blockIdx.x, tid = threadIdx.x;
    const int lane = tid & 63, wave = tid >> 6;
    const float vb = Vb[0];
    float v[8], e[8];
    float mx = -1e30f;
#pragma unroll
    for (int j = 0; j < 8; ++j) {
        v[j] = sacc[b * T_ + j * 256 + tid] + vb;
        out[98304 + b * T_ + j * 256 + tid] = v[j];   // score output
        mx = fmaxf(mx, v[j]);
    }
#pragma unroll
    for (int off = 32; off >= 1; off >>= 1) mx = fmaxf(mx, __shfl_xor(mx, off, 64));
    __shared__ float sm[4], ss[4];
    if (lane == 0) sm[wave] = mx;
    __syncthreads();
    mx = fmaxf(fmaxf(sm[0], sm[1]), fmaxf(sm[2], sm[3]));
    float sum = 0.0f;
#pragma unroll
    for (int j = 0; j < 8; ++j) { e[j] = __expf(v[j] - mx); sum += e[j]; }
#pragma unroll
    for (int off = 32; off >= 1; off >>= 1) sum += __shfl_xor(sum, off, 64);
    if (lane == 0) ss[wave] = sum;
    __syncthreads();
    sum = ss[0] + ss[1] + ss[2] + ss[3];
    const float inv = 1.0f / sum;
#pragma unroll
    for (int j = 0; j < 8; ++j)
        out[32768 + b * T_ + j * 256 + tid] = e[j] * inv;  // attention output
}

// ---------- context = sum_t attn[b,t] * values[b,t,h] (bf16 copy) ----------
// grid 1024 (32 b * 32 chunks of 64 t); 16B/lane loads
__global__ void context_k(const ushort_t* __restrict__ A, const float* __restrict__ attn,
                          float* __restrict__ ctx) {
    const int b = blockIdx.x >> 5, tc = blockIdx.x & 31, tid = threadIdx.x;
    __shared__ float sa[64];
    if (tid < 64) sa[tid] = attn[b * T_ + tc * 64 + tid];
    __syncthreads();
    const int hh = (tid & 127) * 8;   // 8 h-elements per thread
    const int tp = tid >> 7;          // row-pair 0/1
    const ushort_t* base = A + (size_t)(b * T_ + tc * 64 + tp) * KEXT + hh;
    float a[8] = {0, 0, 0, 0, 0, 0, 0, 0};
#pragma unroll 4
    for (int t = 0; t < 64; t += 2) {
        const float w = sa[t + tp];
        uint4 u = *reinterpret_cast<const uint4*>(base + (size_t)t * KEXT);
        a[0] += w * bflo(u.x); a[1] += w * bfhi(u.x);
        a[2] += w * bflo(u.y); a[3] += w * bfhi(u.y);
        a[4] += w * bflo(u.z); a[5] += w * bfhi(u.z);
        a[6] += w * bflo(u.w); a[7] += w * bfhi(u.w);
    }
#pragma unroll
    for (int j = 0; j < 8; ++j)
        atomicAdd(&ctx[b * H_ + hh + j], a[j]);
}

// ---------- launch ----------
extern "C" void kernel_launch(void* const* d_in, const int* in_sizes, int n_in,
                              void* d_out, int out_size, void* d_ws, size_t ws_size,
                              hipStream_t stream) {
    const float* query    = (const float*)d_in[0];
    const float* values   = (const float*)d_in[1];
    const float* prev_att = (const float*)d_in[2];
    const float* W1w      = (const float*)d_in[3];
    const float* W1b      = (const float*)d_in[4];
    const float* W2w      = (const float*)d_in[5];
    const float* W2b      = (const float*)d_in[6];
    const float* Vw       = (const float*)d_in[7];
    const float* Vb       = (const float*)d_in[8];
    const float* convw    = (const float*)d_in[9];
    const float* locp     = (const float*)d_in[10];
    float* out = (float*)d_out;

    char* ws = (char*)d_ws;
    ushort_t* A    = (ushort_t*)(ws);
    ushort_t* Bm   = (ushort_t*)(ws + 138412032);
    float*    bias = (float*)(ws + 140574720);
    float*    sacc = (float*)(ws + 140705792);

    hipMemsetAsync(sacc, 0, BT_ * sizeof(float), stream);
    hipMemsetAsync(out, 0, 32768 * sizeof(float), stream);   // context via atomics

    pack_all<<<1024, 256, 0, stream>>>(values, prev_att, convw, A);
    pack_w_bias<<<1024, 256, 0, stream>>>(W1w, locp, W2w, query, W1b, W2b, Bm, bias);
    score_gemm<<<4096, 256, 0, stream>>>(A, Bm, bias, Vw, sacc);
    softmax_k<<<32, 256, 0, stream>>>(sacc, Vb, out);
    context_k<<<1024, 256, 0, stream>>>(A, out + 32768, out);
}

// Round 4
// 640.426 us; speedup vs baseline: 1.0477x; 1.0477x over previous
//
#include <hip/hip_runtime.h>
#include <cstdint>
#include <cstddef>

typedef unsigned short ushort_t;
typedef __attribute__((ext_vector_type(8))) short short8;    // 8 bf16 (4 VGPRs)
typedef __attribute__((ext_vector_type(4))) float floatx4;

#define B_   32
#define T_   2048
#define H_   1024
#define U_   1024
#define KN_  32
#define KEXT 1056            // H + KN, = 33 * 32
#define BT_  (B_ * T_)       // 65536

// ---------- helpers ----------
__device__ __forceinline__ unsigned int f2bf_u(float f) {
    union { float f; unsigned int u; } v; v.f = f;
    unsigned int u = v.u;
    return (u + 0x7FFFu + ((u >> 16) & 1u)) >> 16;  // RNE
}
__device__ __forceinline__ float bflo(unsigned int u) {
    union { unsigned int u; float f; } v; v.u = u << 16; return v.f;
}
__device__ __forceinline__ float bfhi(unsigned int u) {
    union { unsigned int u; float f; } v; v.u = u & 0xffff0000u; return v.f;
}
__device__ __forceinline__ void async_cp16(const void* g, void* l) {
    __builtin_amdgcn_global_load_lds(
        (const __attribute__((address_space(1))) unsigned int*)g,
        (__attribute__((address_space(3))) unsigned int*)l, 16, 0, 0);
}
__device__ __forceinline__ float fast_tanh(float x) {
    float e = __expf(2.0f * x);
    return 1.0f - 2.0f * __builtin_amdgcn_rcpf(e + 1.0f);
}

// ---------- prep kernels (R2 measured-best forms) ----------
// values (B,T,H) f32 -> A[row][0:1024] bf16; 8 rows per block
__global__ void pack_values(const float* __restrict__ values, ushort_t* __restrict__ A) {
    const int tid = threadIdx.x;
    const size_t base = (size_t)blockIdx.x * 8;
#pragma unroll
    for (int r = 0; r < 8; ++r) {
        const size_t row = base + r;
        float4 v = reinterpret_cast<const float4*>(values + row * H_)[tid];
        ushort4 o;
        o.x = (ushort_t)f2bf_u(v.x); o.y = (ushort_t)f2bf_u(v.y);
        o.z = (ushort_t)f2bf_u(v.z); o.w = (ushort_t)f2bf_u(v.w);
        *reinterpret_cast<ushort4*>(A + row * KEXT + tid * 4) = o;
    }
}

// conv(prev_att, conv_w) -> A[row][1024:1056] bf16 (loc transposed to (b,t,k))
__global__ void conv_pack(const float* __restrict__ prev, const float* __restrict__ convw,
                          ushort_t* __restrict__ A) {
    __shared__ float satt[158];       // 128 + 2*15
    __shared__ float sw[KN_ * 31];
    const int tid = threadIdx.x;
    const int b = blockIdx.y, t0 = blockIdx.x * 128;
    for (int i = tid; i < 158; i += 256) {
        int t = t0 - 15 + i;
        satt[i] = (t >= 0 && t < T_) ? prev[b * T_ + t] : 0.0f;
    }
    for (int i = tid; i < KN_ * 31; i += 256) sw[i] = convw[i];
    __syncthreads();
    for (int idx = tid; idx < 128 * KN_; idx += 256) {
        const int k = idx & 31, tl = idx >> 5;
        float acc = 0.0f;
#pragma unroll
        for (int j = 0; j < 31; ++j) acc += satt[tl + j] * sw[k * 31 + j];
        A[(size_t)(b * T_ + t0 + tl) * KEXT + H_ + k] = (ushort_t)f2bf_u(acc);
    }
}

// per u: pack [W1_w | loc_proj] row to Bm bf16 AND bias[b][u] for all 32 b
__global__ void pack_w_bias(const float* __restrict__ W1w, const float* __restrict__ locp,
                            const float* __restrict__ W2w, const float* __restrict__ q,
                            const float* __restrict__ W1b, const float* __restrict__ W2b,
                            ushort_t* __restrict__ Bm, float* __restrict__ bias) {
    const int u = blockIdx.x, tid = threadIdx.x;
    {
        float4 v = reinterpret_cast<const float4*>(W1w + (size_t)u * H_)[tid];
        ushort4 o;
        o.x = (ushort_t)f2bf_u(v.x); o.y = (ushort_t)f2bf_u(v.y);
        o.z = (ushort_t)f2bf_u(v.z); o.w = (ushort_t)f2bf_u(v.w);
        *reinterpret_cast<ushort4*>(Bm + (size_t)u * KEXT + tid * 4) = o;
    }
    if (tid < 8) {
        float4 w = reinterpret_cast<const float4*>(locp + u * KN_)[tid];
        ushort4 o2;
        o2.x = (ushort_t)f2bf_u(w.x); o2.y = (ushort_t)f2bf_u(w.y);
        o2.z = (ushort_t)f2bf_u(w.z); o2.w = (ushort_t)f2bf_u(w.w);
        *reinterpret_cast<ushort4*>(Bm + (size_t)u * KEXT + H_ + tid * 4) = o2;
    }
    const int lane = tid & 63, wave = tid >> 6;
    const float* wr = W2w + (size_t)u * H_;
    float wv[16];
#pragma unroll
    for (int i = 0; i < 16; ++i) wv[i] = wr[lane + i * 64];
    const float bb = W1b[u] + W2b[u];
#pragma unroll
    for (int j = 0; j < 8; ++j) {
        const int b = wave * 8 + j;
        const float* qr = q + b * H_;
        float acc = 0.0f;
#pragma unroll
        for (int i = 0; i < 16; ++i) acc += wv[i] * qr[lane + i * 64];
#pragma unroll
        for (int off = 32; off >= 1; off >>= 1) acc += __shfl_xor(acc, off, 64);
        if (lane == 0) bias[b * U_ + u] = acc + bb;
    }
}

// ---------- fused score GEMM, BK=64 ----------
// XCD swizzle (xcd keyed to m) + XOR-swizzled conflict-free LDS + two MFMA
// K-steps per barrier pair (halves the vmcnt(0)+s_barrier drain per MFMA).
__global__ __launch_bounds__(256, 2)
void score_gemm(const ushort_t* __restrict__ A, const ushort_t* __restrict__ Bm,
                const float* __restrict__ bias, const float* __restrict__ Vw,
                float* __restrict__ sacc) {
    __shared__ __align__(16) ushort_t lA[128 * 64];  // 16 KB, two 32-k sub-tiles
    __shared__ __align__(16) ushort_t lB[128 * 64];  // 16 KB
    const int tid  = threadIdx.x;
    const int wave = tid >> 6;
    const int lane = tid & 63;

    const int hid  = blockIdx.x;          // 0..4095
    const int xcd  = hid & 7;
    const int slot = hid >> 3;
    const int n_idx = slot & 7;
    const int m_idx = ((slot >> 3) << 3) | xcd;   // 0..511
    const int m0 = m_idx * 128;
    const int n0 = n_idx * 128;

    const int wm = (wave >> 1) * 64;
    const int wn = (wave & 1) * 64;
    const int lr   = lane & 15;
    const int quad = lane >> 4;

    floatx4 acc[4][4] = {};

    const ushort_t* Abase = A + (size_t)m0 * KEXT;
    const ushort_t* Bbase = Bm + (size_t)n0 * KEXT;

    // staging: slot s (0..1023) -> sub = s>>9 (k 0-31 / 32-63), w = s&511,
    // row = w>>2, chunk col c = (w&3)^((w>>3)&3) (conflict-free XOR swizzle)
    int srcOff[4];
#pragma unroll
    for (int j = 0; j < 4; ++j) {
        const int s = j * 256 + wave * 64 + lane;
        const int sub = s >> 9, w = s & 511;
        const int row = w >> 2;
        const int c = (w & 3) ^ ((w >> 3) & 3);
        srcOff[j] = row * KEXT + (sub * 4 + c) * 8;
    }
    int srcOffT[2];
#pragma unroll
    for (int j = 0; j < 2; ++j) {
        const int s = j * 256 + wave * 64 + lane;
        const int row = s >> 2;
        const int c = (s & 3) ^ ((s >> 3) & 3);
        srcOffT[j] = row * KEXT + c * 8;
    }
    // fragment chunk xor (per-lane constant)
    const int cxor = (quad ^ ((lr >> 1) & 3)) * 8;

    for (int kk = 0; kk < 16; ++kk) {
        const int kb = kk * 64;
#pragma unroll
        for (int j = 0; j < 4; ++j) {
            async_cp16(Abase + kb + srcOff[j], lA + j * 2048 + wave * 512);
            async_cp16(Bbase + kb + srcOff[j], lB + j * 2048 + wave * 512);
        }
        __syncthreads();
#pragma unroll
        for (int half = 0; half < 2; ++half) {
            const ushort_t* pA = lA + half * 4096;
            const ushort_t* pB = lB + half * 4096;
            short8 af[4], bfr[4];
#pragma unroll
            for (int mi = 0; mi < 4; ++mi)
                af[mi] = *reinterpret_cast<const short8*>(pA + (wm + mi * 16 + lr) * 32 + cxor);
#pragma unroll
            for (int ni = 0; ni < 4; ++ni)
                bfr[ni] = *reinterpret_cast<const short8*>(pB + (wn + ni * 16 + lr) * 32 + cxor);
#pragma unroll
            for (int mi = 0; mi < 4; ++mi)
#pragma unroll
                for (int ni = 0; ni < 4; ++ni)
                    acc[mi][ni] = __builtin_amdgcn_mfma_f32_16x16x32_bf16(af[mi], bfr[ni], acc[mi][ni], 0, 0, 0);
        }
        __syncthreads();
    }
    // K tail: loc columns k = 1024..1055 (one 32-k step)
    {
#pragma unroll
        for (int j = 0; j < 2; ++j) {
            async_cp16(Abase + 1024 + srcOffT[j], lA + j * 2048 + wave * 512);
            async_cp16(Bbase + 1024 + srcOffT[j], lB + j * 2048 + wave * 512);
        }
        __syncthreads();
        short8 af[4], bfr[4];
#pragma unroll
        for (int mi = 0; mi < 4; ++mi)
            af[mi] = *reinterpret_cast<const short8*>(lA + (wm + mi * 16 + lr) * 32 + cxor);
#pragma unroll
        for (int ni = 0; ni < 4; ++ni)
            bfr[ni] = *reinterpret_cast<const short8*>(lB + (wn + ni * 16 + lr) * 32 + cxor);
#pragma unroll
        for (int mi = 0; mi < 4; ++mi)
#pragma unroll
            for (int ni = 0; ni < 4; ++ni)
                acc[mi][ni] = __builtin_amdgcn_mfma_f32_16x16x32_bf16(af[mi], bfr[ni], acc[mi][ni], 0, 0, 0);
    }

    // epilogue: sum_1 -> tanh -> *Vw -> reduce over u (cols) -> atomic partial score
    const int b = m0 >> 11;
    const float* brow = bias + b * U_;
    float vw[4], bv[4];
#pragma unroll
    for (int ni = 0; ni < 4; ++ni) {
        const int u = n0 + wn + ni * 16 + lr;
        vw[ni] = Vw[u];
        bv[ni] = brow[u];
    }
#pragma unroll
    for (int mi = 0; mi < 4; ++mi) {
#pragma unroll
        for (int r = 0; r < 4; ++r) {
            float s = 0.0f;
#pragma unroll
            for (int ni = 0; ni < 4; ++ni)
                s += vw[ni] * fast_tanh(acc[mi][ni][r] + bv[ni]);
            s += __shfl_xor(s, 1, 64);
            s += __shfl_xor(s, 2, 64);
            s += __shfl_xor(s, 4, 64);
            s += __shfl_xor(s, 8, 64);
            if (lr == 0)
                atomicAdd(&sacc[m0 + wm + mi * 16 + quad * 4 + r], s);
        }
    }
}

// ---------- softmax over T per b; writes score and attn outputs ----------
__global__ void softmax_k(const float* __restrict__ sacc, const float* __restrict__ Vb,
                          float* __restrict__ out) {
    const int b = blockIdx.x, tid = threadIdx.x;
    const int lane = tid & 63, wave = tid >> 6;
    const float vb = Vb[0];
    float v[8], e[8];
    float mx = -1e30f;
#pragma unroll
    for (int j = 0; j < 8; ++j) {
        v[j] = sacc[b * T_ + j * 256 + tid] + vb;
        out[98304 + b * T_ + j * 256 + tid] = v[j];   // score output
        mx = fmaxf(mx, v[j]);
    }
#pragma unroll
    for (int off = 32; off >= 1; off >>= 1) mx = fmaxf(mx, __shfl_xor(mx, off, 64));
    __shared__ float sm[4], ss[4];
    if (lane == 0) sm[wave] = mx;
    __syncthreads();
    mx = fmaxf(fmaxf(sm[0], sm[1]), fmaxf(sm[2], sm[3]));
    float sum = 0.0f;
#pragma unroll
    for (int j = 0; j < 8; ++j) { e[j] = __expf(v[j] - mx); sum += e[j]; }
#pragma unroll
    for (int off = 32; off >= 1; off >>= 1) sum += __shfl_xor(sum, off, 64);
    if (lane == 0) ss[wave] = sum;
    __syncthreads();
    sum = ss[0] + ss[1] + ss[2] + ss[3];
    const float inv = 1.0f / sum;
#pragma unroll
    for (int j = 0; j < 8; ++j)
        out[32768 + b * T_ + j * 256 + tid] = e[j] * inv;  // attention output
}

// ---------- context = sum_t attn[b,t] * values[b,t,h] (bf16 copy) ----------
// grid (16, 32): 512 blocks; 16B/lane loads; 2 t-rows in flight per 256 threads
__global__ void context_k(const ushort_t* __restrict__ A, const float* __restrict__ attn,
                          float* __restrict__ ctx) {
    const int b = blockIdx.y, tc = blockIdx.x, tid = threadIdx.x;
    __shared__ float sa[128];
    if (tid < 128) sa[tid] = attn[b * T_ + tc * 128 + tid];
    __syncthreads();
    const int hh = (tid & 127) * 8;   // 8 h-elements per thread
    const int tp = tid >> 7;          // row-pair 0/1
    const ushort_t* base = A + (size_t)(b * T_ + tc * 128 + tp) * KEXT + hh;
    float a[8] = {0, 0, 0, 0, 0, 0, 0, 0};
    for (int t = 0; t < 128; t += 2) {
        const float w = sa[t + tp];
        uint4 u = *reinterpret_cast<const uint4*>(base + (size_t)t * KEXT);
        a[0] += w * bflo(u.x); a[1] += w * bfhi(u.x);
        a[2] += w * bflo(u.y); a[3] += w * bfhi(u.y);
        a[4] += w * bflo(u.z); a[5] += w * bfhi(u.z);
        a[6] += w * bflo(u.w); a[7] += w * bfhi(u.w);
    }
#pragma unroll
    for (int j = 0; j < 8; ++j)
        atomicAdd(&ctx[b * H_ + hh + j], a[j]);
}

// ---------- launch ----------
extern "C" void kernel_launch(void* const* d_in, const int* in_sizes, int n_in,
                              void* d_out, int out_size, void* d_ws, size_t ws_size,
                              hipStream_t stream) {
    const float* query    = (const float*)d_in[0];
    const float* values   = (const float*)d_in[1];
    const float* prev_att = (const float*)d_in[2];
    const float* W1w      = (const float*)d_in[3];
    const float* W1b      = (const float*)d_in[4];
    const float* W2w      = (const float*)d_in[5];
    const float* W2b      = (const float*)d_in[6];
    const float* Vw       = (const float*)d_in[7];
    const float* Vb       = (const float*)d_in[8];
    const float* convw    = (const float*)d_in[9];
    const float* locp     = (const float*)d_in[10];
    float* out = (float*)d_out;

    char* ws = (char*)d_ws;
    ushort_t* A    = (ushort_t*)(ws);
    ushort_t* Bm   = (ushort_t*)(ws + 138412032);
    float*    bias = (float*)(ws + 140574720);
    float*    sacc = (float*)(ws + 140705792);

    hipMemsetAsync(sacc, 0, BT_ * sizeof(float), stream);
    hipMemsetAsync(out, 0, 32768 * sizeof(float), stream);   // context via atomics

    pack_values<<<BT_ / 8, 256, 0, stream>>>(values, A);
    conv_pack<<<dim3(16, 32), 256, 0, stream>>>(prev_att, convw, A);
    pack_w_bias<<<1024, 256, 0, stream>>>(W1w, locp, W2w, query, W1b, W2b, Bm, bias);
    score_gemm<<<4096, 256, 0, stream>>>(A, Bm, bias, Vw, sacc);
    softmax_k<<<32, 256, 0, stream>>>(sacc, Vb, out);
    context_k<<<dim3(16, 32), 256, 0, stream>>>(A, out + 32768, out);
}